// Round 2
// baseline (3702.101 us; speedup 1.0000x reference)
//
#include <hip/hip_runtime.h>
#include <math.h>

#define NUM_I 100
#define NZ    16
#define NCAND (NUM_I * NZ)
#define F32_EPS 1.1920928955078125e-07f
#define NBINS 32768
#define BIN_SHIFT 17

static __device__ __forceinline__ float rfl_f(float v) {
    return __int_as_float(__builtin_amdgcn_readfirstlane(__float_as_int(v)));
}

// order-preserving float->bin map (top 15 bits of monotone key)
static __device__ __forceinline__ unsigned bin_of(float v) {
    unsigned u = __float_as_uint(v);
    unsigned m = ((unsigned)((int)u >> 31)) | 0x80000000u;
    return (u ^ m) >> BIN_SHIFT;
}

// ---------------- zero the histogram (ws is poisoned 0xAA every launch) ----------------
__global__ void k_zero(unsigned* __restrict__ hist) {
    hist[blockIdx.x * 256 + threadIdx.x] = 0u;
}

// ---------------- K1: per-block min/max partials + global histogram ----------------
__global__ __launch_bounds__(256) void k_minmax_hist(const float* __restrict__ x, int n4,
                                                     float* __restrict__ pmin,
                                                     float* __restrict__ pmax,
                                                     unsigned* __restrict__ hist) {
    int tid = blockIdx.x * blockDim.x + threadIdx.x;
    int stride = gridDim.x * blockDim.x;
    const float4* x4 = (const float4*)x;
    float lmin = 3.0e38f, lmax = -3.0e38f;
    for (int i = tid; i < n4; i += stride) {
        float4 v = x4[i];
        lmin = fminf(lmin, fminf(fminf(v.x, v.y), fminf(v.z, v.w)));
        lmax = fmaxf(lmax, fmaxf(fmaxf(v.x, v.y), fmaxf(v.z, v.w)));
        atomicAdd(&hist[bin_of(v.x)], 1u);
        atomicAdd(&hist[bin_of(v.y)], 1u);
        atomicAdd(&hist[bin_of(v.z)], 1u);
        atomicAdd(&hist[bin_of(v.w)], 1u);
    }
    #pragma unroll
    for (int off = 32; off > 0; off >>= 1) {
        lmin = fminf(lmin, __shfl_xor(lmin, off));
        lmax = fmaxf(lmax, __shfl_xor(lmax, off));
    }
    __shared__ float smin[4], smax[4];
    int w = threadIdx.x >> 6;
    if ((threadIdx.x & 63) == 0) { smin[w] = lmin; smax[w] = lmax; }
    __syncthreads();
    if (threadIdx.x == 0) {
        pmin[blockIdx.x] = fminf(fminf(smin[0], smin[1]), fminf(smin[2], smin[3]));
        pmax[blockIdx.x] = fmaxf(fmaxf(smax[0], smax[1]), fmaxf(smax[2], smax[3]));
    }
}

// ---------------- K2: exclusive scan of hist -> bin_start + cursor ----------------
__global__ __launch_bounds__(256) void k_scan(const unsigned* __restrict__ hist,
                                              unsigned* __restrict__ bin_start,
                                              unsigned* __restrict__ cursor) {
    __shared__ unsigned spart[257];
    int t = threadIdx.x;
    unsigned s = 0;
    const int per = NBINS / 256;  // 128
    for (int i = 0; i < per; i++) s += hist[t * per + i];
    __shared__ unsigned part[256];
    part[t] = s;
    __syncthreads();
    if (t == 0) {
        unsigned r = 0;
        for (int i = 0; i < 256; i++) { spart[i] = r; r += part[i]; }
        spart[256] = r;
    }
    __syncthreads();
    unsigned run = spart[t];
    for (int i = 0; i < per; i++) {
        int b = t * per + i;
        bin_start[b] = run;
        cursor[b] = run;
        run += hist[b];
    }
    if (t == 255) bin_start[NBINS] = run;   // == n
}

// ---------------- K3: scatter x into bin-grouped storage ----------------
__global__ __launch_bounds__(256) void k_scatter(const float* __restrict__ x, int n4,
                                                 unsigned* __restrict__ cursor,
                                                 float* __restrict__ y) {
    int tid = blockIdx.x * blockDim.x + threadIdx.x;
    int stride = gridDim.x * blockDim.x;
    const float4* x4 = (const float4*)x;
    for (int i = tid; i < n4; i += stride) {
        float4 v = x4[i];
        unsigned p0 = atomicAdd(&cursor[bin_of(v.x)], 1u); y[p0] = v.x;
        unsigned p1 = atomicAdd(&cursor[bin_of(v.y)], 1u); y[p1] = v.y;
        unsigned p2 = atomicAdd(&cursor[bin_of(v.z)], 1u); y[p2] = v.z;
        unsigned p3 = atomicAdd(&cursor[bin_of(v.w)], 1u); y[p3] = v.w;
    }
}

// ---------------- K4: per-bin double sums (S1 = sum x, S2 = sum x^2) ----------------
__global__ __launch_bounds__(256) void k_binsums(const float* __restrict__ y,
                                                 const unsigned* __restrict__ bin_start,
                                                 double* __restrict__ binS1,
                                                 double* __restrict__ binS2) {
    int wid = blockIdx.x * 4 + (threadIdx.x >> 6);
    int nwaves = gridDim.x * 4;
    int lane = threadIdx.x & 63;
    for (int b = wid; b < NBINS; b += nwaves) {
        unsigned beg = bin_start[b], end = bin_start[b + 1];
        double s1 = 0.0, s2 = 0.0;
        for (unsigned i = beg + lane; i < end; i += 64) {
            double v = (double)y[i];
            s1 += v;
            s2 += v * v;
        }
        #pragma unroll
        for (int off = 32; off > 0; off >>= 1) {
            s1 += __shfl_xor(s1, off);
            s2 += __shfl_xor(s2, off);
        }
        if (lane == 0) { binS1[b] = s1; binS2[b] = s2; }
    }
}

// ---------------- K5: exclusive double prefix over bins ----------------
__global__ __launch_bounds__(256) void k_prefix(const double* __restrict__ binS1,
                                                const double* __restrict__ binS2,
                                                double* __restrict__ P1,
                                                double* __restrict__ P2) {
    __shared__ double p1[256], p2[256], sp1[257], sp2[257];
    int t = threadIdx.x;
    const int per = NBINS / 256;
    double a1 = 0.0, a2 = 0.0;
    for (int i = 0; i < per; i++) { a1 += binS1[t * per + i]; a2 += binS2[t * per + i]; }
    p1[t] = a1; p2[t] = a2;
    __syncthreads();
    if (t == 0) {
        double r1 = 0.0, r2 = 0.0;
        for (int i = 0; i < 256; i++) { sp1[i] = r1; sp2[i] = r2; r1 += p1[i]; r2 += p2[i]; }
        sp1[256] = r1; sp2[256] = r2;
    }
    __syncthreads();
    double r1 = sp1[t], r2 = sp2[t];
    for (int i = 0; i < per; i++) {
        int b = t * per + i;
        P1[b] = r1; P2[b] = r2;
        r1 += binS1[b]; r2 += binS2[b];
    }
    if (t == 255) { P1[NBINS] = r1; P2[NBINS] = r2; }
}

// ---------------- K6: final min/max + candidate params ----------------
__global__ __launch_bounds__(256) void k_params(const float* __restrict__ pmin,
                                                const float* __restrict__ pmax, int nb,
                                                float4* __restrict__ params,
                                                float2* __restrict__ ranges,
                                                double* __restrict__ score,
                                                float* __restrict__ mm) {
#pragma clang fp contract(off)
    __shared__ float smin[256], smax[256];
    float lmin = 3.0e38f, lmax = -3.0e38f;
    for (int i = threadIdx.x; i < nb; i += 256) {
        lmin = fminf(lmin, pmin[i]);
        lmax = fmaxf(lmax, pmax[i]);
    }
    smin[threadIdx.x] = lmin; smax[threadIdx.x] = lmax;
    __syncthreads();
    for (int s = 128; s > 0; s >>= 1) {
        if (threadIdx.x < s) {
            smin[threadIdx.x] = fminf(smin[threadIdx.x], smin[threadIdx.x + s]);
            smax[threadIdx.x] = fmaxf(smax[threadIdx.x], smax[threadIdx.x + s]);
        }
        __syncthreads();
    }
    float x_min = smin[0], x_max = smax[0];
    if (threadIdx.x == 0) { mm[0] = x_min; mm[1] = x_max; }

    float xrange = x_max - x_min;
    float step = xrange / 100.0f;
    for (int c = threadIdx.x; c < NCAND; c += 256) {
        int ii = c >> 4;
        int z  = c & 15;
        float fi = (float)(ii + 1);
        float tmp_max   = step * fi;
        float tmp_delta = tmp_max / 15.0f;
        float t = (float)z * tmp_delta;
        float new_min = fmaxf(-t, x_min);
        float new_max = fminf(tmp_max - t, x_max);
        float min_neg = fminf(new_min, 0.0f);
        float max_pos = fmaxf(new_max, 0.0f);
        float scale = fmaxf((max_pos - min_neg) / 15.0f, F32_EPS);
        float zp = 0.0f - rintf(min_neg / scale);
        zp = fminf(fmaxf(zp, 0.0f), 15.0f);
        float inv = (float)(1.0 / (double)scale);
        params[c] = make_float4(scale, inv, 0.0f - zp, 15.0f - zp);
        ranges[c] = make_float2(new_min, new_max);
        score[c]  = 0.0;
    }
}

// ---------------- K7: analytic scorer — one wave per candidate ----------------
__global__ __launch_bounds__(256) void k_score2(const float* __restrict__ y,
                                                const unsigned* __restrict__ bin_start,
                                                const double* __restrict__ P1,
                                                const double* __restrict__ P2,
                                                const float4* __restrict__ params,
                                                double* __restrict__ score) {
    int wid = blockIdx.x * 4 + (threadIdx.x >> 6);
    if (wid >= NCAND) return;
    int lane = threadIdx.x & 63;
    float4 p = params[wid];
    float s = rfl_f(p.x);
    int zi = (int)(0.0f - rfl_f(p.z));      // z = -lo
    double sd = (double)s;

    double prevC = 0.0, prev1 = 0.0, prev2 = 0.0;
    double sc = 0.0;
    for (int j = 0; j <= 15; j++) {
        double Cc, C1, C2;
        if (j < 15) {
            int m = j - zi;
            double t = ((double)m + 0.5) * sd;   // boundary between level m and m+1
            float tf = (float)t;
            unsigned b = bin_of(tf);
            unsigned beg = bin_start[b], end = bin_start[b + 1];
            unsigned c = 0; double s1 = 0.0, s2 = 0.0;
            for (unsigned i = beg + lane; i < end; i += 64) {
                double v = (double)y[i];
                if (v < t) { c++; s1 += v; s2 += v * v; }
            }
            #pragma unroll
            for (int off = 32; off > 0; off >>= 1) {
                c  += __shfl_xor(c, off);
                s1 += __shfl_xor(s1, off);
                s2 += __shfl_xor(s2, off);
            }
            Cc = (double)bin_start[b] + (double)c;
            C1 = P1[b] + s1;
            C2 = P2[b] + s2;
        } else {
            Cc = (double)bin_start[NBINS];
            C1 = P1[NBINS];
            C2 = P2[NBINS];
        }
        double m  = (double)(j - zi);
        double ms = m * sd;
        sc += (Cc - prevC) * ms * ms - 2.0 * ms * (C1 - prev1) + (C2 - prev2);
        prevC = Cc; prev1 = C1; prev2 = C2;
    }
    if (lane == 0) score[wid] = sc;
}

// ---------------- K8: argmin with exact reference tie-break semantics ----------------
__global__ void k_final(const double* __restrict__ score,
                        const float2* __restrict__ ranges,
                        const float* __restrict__ mm,
                        float* __restrict__ out, int n) {
    if (blockIdx.x == 0 && threadIdx.x == 0) {
        double best = 1.0e10;
        float bmin = mm[0], bmax = mm[1];
        double inv_n = 1.0 / (double)n;
        for (int c = 0; c < NCAND; c++) {
            double sc = score[c] * inv_n;
            if (sc < best) { best = sc; bmin = ranges[c].x; bmax = ranges[c].y; }
        }
        out[0] = bmin;
        out[1] = bmax;
    }
}

// ---------------- fallback brute-force scorer (round-1, proven) ----------------
__global__ __launch_bounds__(256) void k_score_bf(const float* __restrict__ x, int n4,
                                                  const float4* __restrict__ params,
                                                  double* __restrict__ score) {
    const int tid = blockIdx.x * 256 + threadIdx.x;
    const int T = gridDim.x * 256;
    const float4* x4 = (const float4*)x;
    float xs[16];
    #pragma unroll
    for (int k = 0; k < 4; k++) {
        int i4 = tid + k * T;
        float4 v;
        if (i4 < n4) v = x4[i4];
        else { v.x = 0.0f; v.y = 0.0f; v.z = 0.0f; v.w = 0.0f; }
        xs[4*k+0] = v.x; xs[4*k+1] = v.y; xs[4*k+2] = v.z; xs[4*k+3] = v.w;
    }
    int c = (int)((blockIdx.x * 37u) % NCAND);
    for (int k = 0; k < NCAND; k++) {
        float4 p = params[c];
        float s   = rfl_f(p.x);
        float inv = rfl_f(p.y);
        float lo  = rfl_f(p.z);
        float hi  = rfl_f(p.w);
        float acc = 0.0f;
        #pragma unroll
        for (int e = 0; e < 16; e++) {
            float r = rintf(xs[e] * inv);
            r = fminf(fmaxf(r, lo), hi);
            float d = fmaf(r, s, -xs[e]);
            acc = fmaf(d, d, acc);
        }
        #pragma unroll
        for (int off = 32; off > 0; off >>= 1)
            acc += __shfl_xor(acc, off);
        if ((threadIdx.x & 63) == 0)
            atomicAdd(&score[c], (double)acc);
        c++; if (c >= NCAND) c -= NCAND;
    }
}

extern "C" void kernel_launch(void* const* d_in, const int* in_sizes, int n_in,
                              void* d_out, int out_size, void* d_ws, size_t ws_size,
                              hipStream_t stream) {
    const float* x = (const float*)d_in[0];
    int n  = in_sizes[0];          // 4194304
    int n4 = n / 4;
    float* out = (float*)d_out;

    // ---- workspace layout (16B-aligned first, then 8B, then 4B) ----
    char* w = (char*)d_ws;
    float4*   params    = (float4*)w;    w += sizeof(float4) * NCAND;
    double*   binS1     = (double*)w;    w += sizeof(double) * NBINS;
    double*   binS2     = (double*)w;    w += sizeof(double) * NBINS;
    double*   P1        = (double*)w;    w += sizeof(double) * (NBINS + 1);
    double*   P2        = (double*)w;    w += sizeof(double) * (NBINS + 1);
    double*   score     = (double*)w;    w += sizeof(double) * NCAND;
    float2*   ranges    = (float2*)w;    w += sizeof(float2) * NCAND;
    float*    y         = (float*)w;     w += sizeof(float) * (size_t)n;
    unsigned* hist      = (unsigned*)w;  w += sizeof(unsigned) * NBINS;
    unsigned* bin_start = (unsigned*)w;  w += sizeof(unsigned) * (NBINS + 1);
    unsigned* cursor    = (unsigned*)w;  w += sizeof(unsigned) * NBINS;
    float*    pmin      = (float*)w;     w += sizeof(float) * 1024;
    float*    pmax      = (float*)w;     w += sizeof(float) * 1024;
    float*    mm        = (float*)w;     w += sizeof(float) * 2;
    size_t needed = (size_t)(w - (char*)d_ws);

    const int MMBLOCKS = 1024;
    if (ws_size >= needed) {
        // ---- analytic path ----
        k_zero<<<NBINS / 256, 256, 0, stream>>>(hist);
        k_minmax_hist<<<MMBLOCKS, 256, 0, stream>>>(x, n4, pmin, pmax, hist);
        k_scan<<<1, 256, 0, stream>>>(hist, bin_start, cursor);
        k_scatter<<<1024, 256, 0, stream>>>(x, n4, cursor, y);
        k_binsums<<<256, 256, 0, stream>>>(y, bin_start, binS1, binS2);
        k_prefix<<<1, 256, 0, stream>>>(binS1, binS2, P1, P2);
        k_params<<<1, 256, 0, stream>>>(pmin, pmax, MMBLOCKS, params, ranges, score, mm);
        k_score2<<<NCAND / 4, 256, 0, stream>>>(y, bin_start, P1, P2, params, score);
        k_final<<<1, 64, 0, stream>>>(score, ranges, mm, out, n);
    } else {
        // ---- fallback: round-1 brute force (proven) ----
        char* wb = (char*)d_ws;
        float4* paramsB = (float4*)wb;  wb += sizeof(float4) * NCAND;
        float2* rangesB = (float2*)wb;  wb += sizeof(float2) * NCAND;
        double* scoreB  = (double*)wb;  wb += sizeof(double) * NCAND;
        float*  pminB   = (float*)wb;   wb += sizeof(float) * 1024;
        float*  pmaxB   = (float*)wb;   wb += sizeof(float) * 1024;
        float*  mmB     = (float*)wb;   wb += sizeof(float) * 2;
        k_minmax_hist<<<MMBLOCKS, 256, 0, stream>>>(x, n4, pminB, pmaxB, (unsigned*)scoreB); // hist unused target is scoreB pre-zero; overwritten below
        k_params<<<1, 256, 0, stream>>>(pminB, pmaxB, MMBLOCKS, paramsB, rangesB, scoreB, mmB);
        int nthreads = (n4 + 3) / 4;
        int blocks = (nthreads + 255) / 256;
        k_score_bf<<<blocks, 256, 0, stream>>>(x, n4, paramsB, scoreB);
        k_final<<<1, 64, 0, stream>>>(scoreB, rangesB, mmB, out, n);
    }
}

// Round 3
// 624.282 us; speedup vs baseline: 5.9302x; 5.9302x over previous
//
#include <hip/hip_runtime.h>
#include <math.h>

#define NUM_I 100
#define NZ    16
#define NCAND (NUM_I * NZ)
#define NB    1024           // value-linear bins
#define F32_EPS 1.1920928955078125e-07f

static __device__ __forceinline__ float rfl_f(float v) {
    return __int_as_float(__builtin_amdgcn_readfirstlane(__float_as_int(v)));
}

// monotone non-decreasing value->bin map (exactness of prefix+partial relies only on monotonicity)
static __device__ __forceinline__ int bin_of(float v, float lo, float invw) {
    int b = (int)floorf((v - lo) * invw);
    return min(max(b, 0), NB - 1);
}

// ---------------- K1: per-block min/max partials ----------------
__global__ __launch_bounds__(256) void k_minmax(const float* __restrict__ x, int n4,
                                                float* __restrict__ pmin,
                                                float* __restrict__ pmax) {
    int tid = blockIdx.x * blockDim.x + threadIdx.x;
    int stride = gridDim.x * blockDim.x;
    const float4* x4 = (const float4*)x;
    float lmin = 3.0e38f, lmax = -3.0e38f;
    for (int i = tid; i < n4; i += stride) {
        float4 v = x4[i];
        lmin = fminf(lmin, fminf(fminf(v.x, v.y), fminf(v.z, v.w)));
        lmax = fmaxf(lmax, fmaxf(fmaxf(v.x, v.y), fmaxf(v.z, v.w)));
    }
    #pragma unroll
    for (int off = 32; off > 0; off >>= 1) {
        lmin = fminf(lmin, __shfl_xor(lmin, off));
        lmax = fmaxf(lmax, __shfl_xor(lmax, off));
    }
    __shared__ float smin[4], smax[4];
    int w = threadIdx.x >> 6;
    if ((threadIdx.x & 63) == 0) { smin[w] = lmin; smax[w] = lmax; }
    __syncthreads();
    if (threadIdx.x == 0) {
        pmin[blockIdx.x] = fminf(fminf(smin[0], smin[1]), fminf(smin[2], smin[3]));
        pmax[blockIdx.x] = fmaxf(fmaxf(smax[0], smax[1]), fmaxf(smax[2], smax[3]));
    }
}

// ---------------- K2: finalize min/max, binning params, candidate params, zero hist+score ----------------
__global__ __launch_bounds__(256) void k_setup(const float* __restrict__ pmin,
                                               const float* __restrict__ pmax, int nb,
                                               float4* __restrict__ params,
                                               float2* __restrict__ ranges,
                                               double* __restrict__ score,
                                               float* __restrict__ mm,
                                               unsigned* __restrict__ hist) {
#pragma clang fp contract(off)
    __shared__ float smin[256], smax[256];
    float lmin = 3.0e38f, lmax = -3.0e38f;
    for (int i = threadIdx.x; i < nb; i += 256) {
        lmin = fminf(lmin, pmin[i]);
        lmax = fmaxf(lmax, pmax[i]);
    }
    smin[threadIdx.x] = lmin; smax[threadIdx.x] = lmax;
    __syncthreads();
    for (int s = 128; s > 0; s >>= 1) {
        if (threadIdx.x < s) {
            smin[threadIdx.x] = fminf(smin[threadIdx.x], smin[threadIdx.x + s]);
            smax[threadIdx.x] = fmaxf(smax[threadIdx.x], smax[threadIdx.x + s]);
        }
        __syncthreads();
    }
    float x_min = smin[0], x_max = smax[0];
    if (threadIdx.x == 0) {
        mm[0] = x_min; mm[1] = x_max;
        float range = x_max - x_min;
        mm[2] = x_min;                                  // lo
        mm[3] = (range > 0.0f) ? ((float)NB / range) : 0.0f;  // invw
    }

    float xrange = x_max - x_min;
    float step = xrange / 100.0f;
    for (int c = threadIdx.x; c < NCAND; c += 256) {
        int ii = c >> 4;
        int z  = c & 15;
        float fi = (float)(ii + 1);
        float tmp_max   = step * fi;
        float tmp_delta = tmp_max / 15.0f;
        float t = (float)z * tmp_delta;
        float new_min = fmaxf(-t, x_min);
        float new_max = fminf(tmp_max - t, x_max);
        float min_neg = fminf(new_min, 0.0f);
        float max_pos = fmaxf(new_max, 0.0f);
        float scale = fmaxf((max_pos - min_neg) / 15.0f, F32_EPS);
        float zp = 0.0f - rintf(min_neg / scale);
        zp = fminf(fmaxf(zp, 0.0f), 15.0f);
        float inv = (float)(1.0 / (double)scale);
        params[c] = make_float4(scale, inv, 0.0f - zp, 15.0f - zp);
        ranges[c] = make_float2(new_min, new_max);
        score[c]  = 0.0;
    }
    for (int b = threadIdx.x; b < NB; b += 256) hist[b] = 0u;
}

// ---------------- K3: global count histogram via LDS privatization ----------------
__global__ __launch_bounds__(256) void k_hist(const float* __restrict__ x, int n4,
                                              const float* __restrict__ mm,
                                              unsigned* __restrict__ hist) {
    __shared__ unsigned h[NB];
    for (int b = threadIdx.x; b < NB; b += 256) h[b] = 0u;
    __syncthreads();
    float lo = mm[2], invw = mm[3];
    int tid = blockIdx.x * 256 + threadIdx.x;
    int stride = gridDim.x * 256;
    const float4* x4 = (const float4*)x;
    for (int i = tid; i < n4; i += stride) {
        float4 v = x4[i];
        atomicAdd(&h[bin_of(v.x, lo, invw)], 1u);
        atomicAdd(&h[bin_of(v.y, lo, invw)], 1u);
        atomicAdd(&h[bin_of(v.z, lo, invw)], 1u);
        atomicAdd(&h[bin_of(v.w, lo, invw)], 1u);
    }
    __syncthreads();
    for (int b = threadIdx.x; b < NB; b += 256) {
        unsigned c = h[b];
        if (c) atomicAdd(&hist[b], c);
    }
}

// ---------------- K4: exclusive scan -> bin_start + cursor ----------------
__global__ __launch_bounds__(256) void k_scan(const unsigned* __restrict__ hist,
                                              unsigned* __restrict__ bin_start,
                                              unsigned* __restrict__ cursor) {
    __shared__ unsigned part[256], spart[257];
    int t = threadIdx.x;
    const int per = NB / 256;  // 4
    unsigned s = 0;
    for (int i = 0; i < per; i++) s += hist[t * per + i];
    part[t] = s;
    __syncthreads();
    if (t == 0) {
        unsigned r = 0;
        for (int i = 0; i < 256; i++) { spart[i] = r; r += part[i]; }
        spart[256] = r;
    }
    __syncthreads();
    unsigned run = spart[t];
    for (int i = 0; i < per; i++) {
        int b = t * per + i;
        bin_start[b] = run;
        cursor[b] = run;
        run += hist[b];
    }
    if (t == 255) bin_start[NB] = run;   // == n
}

// ---------------- K5: block-aggregated scatter ----------------
// Block owns a contiguous segment; per-element atomics are LDS-only.
__global__ __launch_bounds__(256) void k_scatter(const float* __restrict__ x, int n4,
                                                 const float* __restrict__ mm,
                                                 unsigned* __restrict__ cursor,
                                                 float* __restrict__ y) {
    __shared__ unsigned cnt[NB];
    for (int b = threadIdx.x; b < NB; b += 256) cnt[b] = 0u;
    __syncthreads();
    float lo = mm[2], invw = mm[3];
    const float4* x4 = (const float4*)x;
    int seg4 = n4 / gridDim.x;                       // 4096
    int base4 = blockIdx.x * seg4;
    // phase 1: local count
    for (int k = 0; k < seg4 / 256; k++) {
        float4 v = x4[base4 + k * 256 + threadIdx.x];
        atomicAdd(&cnt[bin_of(v.x, lo, invw)], 1u);
        atomicAdd(&cnt[bin_of(v.y, lo, invw)], 1u);
        atomicAdd(&cnt[bin_of(v.z, lo, invw)], 1u);
        atomicAdd(&cnt[bin_of(v.w, lo, invw)], 1u);
    }
    __syncthreads();
    // phase 2: one returning global atomic per nonempty bin -> block base; store into cnt as cursor
    for (int q = 0; q < NB / 256; q++) {
        int b = threadIdx.x + q * 256;
        unsigned c = cnt[b];
        unsigned base = c ? atomicAdd(&cursor[b], c) : 0u;
        __syncthreads();     // all reads of cnt done before overwrite
        cnt[b] = base;
        __syncthreads();
    }
    // phase 3: place elements via LDS returning atomics
    for (int k = 0; k < seg4 / 256; k++) {
        float4 v = x4[base4 + k * 256 + threadIdx.x];
        unsigned p0 = atomicAdd(&cnt[bin_of(v.x, lo, invw)], 1u); y[p0] = v.x;
        unsigned p1 = atomicAdd(&cnt[bin_of(v.y, lo, invw)], 1u); y[p1] = v.y;
        unsigned p2 = atomicAdd(&cnt[bin_of(v.z, lo, invw)], 1u); y[p2] = v.z;
        unsigned p3 = atomicAdd(&cnt[bin_of(v.w, lo, invw)], 1u); y[p3] = v.w;
    }
}

// ---------------- K6: per-bin double sums over grouped y (no atomics) ----------------
__global__ __launch_bounds__(256) void k_binsums(const float* __restrict__ y,
                                                 const unsigned* __restrict__ bin_start,
                                                 double* __restrict__ binS1,
                                                 double* __restrict__ binS2) {
    int b = blockIdx.x * 4 + (threadIdx.x >> 6);     // one wave per bin, grid covers NB
    if (b >= NB) return;
    int lane = threadIdx.x & 63;
    unsigned beg = bin_start[b], end = bin_start[b + 1];
    double s1 = 0.0, s2 = 0.0;
    for (unsigned i = beg + lane; i < end; i += 64) {
        double v = (double)y[i];
        s1 += v;
        s2 += v * v;
    }
    #pragma unroll
    for (int off = 32; off > 0; off >>= 1) {
        s1 += __shfl_xor(s1, off);
        s2 += __shfl_xor(s2, off);
    }
    if (lane == 0) { binS1[b] = s1; binS2[b] = s2; }
}

// ---------------- K7: exclusive double prefix over bins ----------------
__global__ __launch_bounds__(256) void k_prefix(const double* __restrict__ binS1,
                                                const double* __restrict__ binS2,
                                                double* __restrict__ P1,
                                                double* __restrict__ P2) {
    __shared__ double p1[256], p2[256], sp1[257], sp2[257];
    int t = threadIdx.x;
    const int per = NB / 256;  // 4
    double a1 = 0.0, a2 = 0.0;
    for (int i = 0; i < per; i++) { a1 += binS1[t * per + i]; a2 += binS2[t * per + i]; }
    p1[t] = a1; p2[t] = a2;
    __syncthreads();
    if (t == 0) {
        double r1 = 0.0, r2 = 0.0;
        for (int i = 0; i < 256; i++) { sp1[i] = r1; sp2[i] = r2; r1 += p1[i]; r2 += p2[i]; }
        sp1[256] = r1; sp2[256] = r2;
    }
    __syncthreads();
    double r1 = sp1[t], r2 = sp2[t];
    for (int i = 0; i < per; i++) {
        int b = t * per + i;
        P1[b] = r1; P2[b] = r2;
        r1 += binS1[b]; r2 += binS2[b];
    }
    if (t == 255) { P1[NB] = r1; P2[NB] = r2; }
}

// ---------------- K8: analytic scorer — one block (4 waves) per candidate ----------------
__global__ __launch_bounds__(256) void k_score2(const float* __restrict__ y,
                                                const unsigned* __restrict__ bin_start,
                                                const double* __restrict__ P1,
                                                const double* __restrict__ P2,
                                                const float4* __restrict__ params,
                                                const float* __restrict__ mm,
                                                double* __restrict__ score) {
    int c = blockIdx.x;
    int w = threadIdx.x >> 6, lane = threadIdx.x & 63;
    float lo = mm[2], invw = mm[3];
    float4 p = params[c];
    float s = p.x;
    int zi = (int)(0.0f - p.z);
    double sd = (double)s;

    __shared__ double sC[15], sS1[15], sS2[15];
    __shared__ int sB[15];

    for (int j = w; j < 15; j += 4) {
        int m = j - zi;
        double td = ((double)m + 0.5) * sd;
        float tf = (float)td;                     // float threshold, consistent with float compare
        int b = bin_of(tf, lo, invw);
        unsigned beg = bin_start[b], end = bin_start[b + 1];
        unsigned cc = 0; double s1 = 0.0, s2 = 0.0;
        for (unsigned i = beg + lane; i < end; i += 64) {
            float v = y[i];
            if (v < tf) { cc++; double vd = (double)v; s1 += vd; s2 += vd * vd; }
        }
        #pragma unroll
        for (int off = 32; off > 0; off >>= 1) {
            cc += __shfl_xor(cc, off);
            s1 += __shfl_xor(s1, off);
            s2 += __shfl_xor(s2, off);
        }
        if (lane == 0) { sB[j] = b; sC[j] = (double)cc; sS1[j] = s1; sS2[j] = s2; }
    }
    __syncthreads();
    if (threadIdx.x == 0) {
        double prevC = 0.0, prev1 = 0.0, prev2 = 0.0, sc = 0.0;
        double nTot  = (double)bin_start[NB];
        for (int j = 0; j <= 15; j++) {
            double Cc, C1, C2;
            if (j < 15) {
                int b = sB[j];
                Cc = (double)bin_start[b] + sC[j];
                C1 = P1[b] + sS1[j];
                C2 = P2[b] + sS2[j];
            } else {
                Cc = nTot; C1 = P1[NB]; C2 = P2[NB];
            }
            double ms = (double)(j - zi) * sd;
            sc += (Cc - prevC) * ms * ms - 2.0 * ms * (C1 - prev1) + (C2 - prev2);
            prevC = Cc; prev1 = C1; prev2 = C2;
        }
        score[c] = sc;
    }
}

// ---------------- K9: argmin with exact reference tie-break semantics ----------------
__global__ void k_final(const double* __restrict__ score,
                        const float2* __restrict__ ranges,
                        const float* __restrict__ mm,
                        float* __restrict__ out, int n) {
    if (blockIdx.x == 0 && threadIdx.x == 0) {
        double best = 1.0e10;
        float bmin = mm[0], bmax = mm[1];
        double inv_n = 1.0 / (double)n;
        for (int c = 0; c < NCAND; c++) {
            double sc = score[c] * inv_n;
            if (sc < best) { best = sc; bmin = ranges[c].x; bmax = ranges[c].y; }
        }
        out[0] = bmin;
        out[1] = bmax;
    }
}

// ---------------- fallback brute-force scorer (round-1, proven) ----------------
__global__ __launch_bounds__(256) void k_score_bf(const float* __restrict__ x, int n4,
                                                  const float4* __restrict__ params,
                                                  double* __restrict__ score) {
    const int tid = blockIdx.x * 256 + threadIdx.x;
    const int T = gridDim.x * 256;
    const float4* x4 = (const float4*)x;
    float xs[16];
    #pragma unroll
    for (int k = 0; k < 4; k++) {
        int i4 = tid + k * T;
        float4 v;
        if (i4 < n4) v = x4[i4];
        else { v.x = 0.0f; v.y = 0.0f; v.z = 0.0f; v.w = 0.0f; }
        xs[4*k+0] = v.x; xs[4*k+1] = v.y; xs[4*k+2] = v.z; xs[4*k+3] = v.w;
    }
    int c = (int)((blockIdx.x * 37u) % NCAND);
    for (int k = 0; k < NCAND; k++) {
        float4 p = params[c];
        float s   = rfl_f(p.x);
        float inv = rfl_f(p.y);
        float lo  = rfl_f(p.z);
        float hi  = rfl_f(p.w);
        float acc = 0.0f;
        #pragma unroll
        for (int e = 0; e < 16; e++) {
            float r = rintf(xs[e] * inv);
            r = fminf(fmaxf(r, lo), hi);
            float d = fmaf(r, s, -xs[e]);
            acc = fmaf(d, d, acc);
        }
        #pragma unroll
        for (int off = 32; off > 0; off >>= 1)
            acc += __shfl_xor(acc, off);
        if ((threadIdx.x & 63) == 0)
            atomicAdd(&score[c], (double)acc);
        c++; if (c >= NCAND) c -= NCAND;
    }
}

extern "C" void kernel_launch(void* const* d_in, const int* in_sizes, int n_in,
                              void* d_out, int out_size, void* d_ws, size_t ws_size,
                              hipStream_t stream) {
    const float* x = (const float*)d_in[0];
    int n  = in_sizes[0];          // 4194304
    int n4 = n / 4;
    float* out = (float*)d_out;

    // ---- workspace layout: small arrays first, big y last ----
    char* w = (char*)d_ws;
    float4*   params    = (float4*)w;    w += sizeof(float4) * NCAND;
    double*   binS1     = (double*)w;    w += sizeof(double) * NB;
    double*   binS2     = (double*)w;    w += sizeof(double) * NB;
    double*   P1        = (double*)w;    w += sizeof(double) * (NB + 1);
    double*   P2        = (double*)w;    w += sizeof(double) * (NB + 1);
    double*   score     = (double*)w;    w += sizeof(double) * NCAND;
    float2*   ranges    = (float2*)w;    w += sizeof(float2) * NCAND;
    unsigned* hist      = (unsigned*)w;  w += sizeof(unsigned) * NB;
    unsigned* bin_start = (unsigned*)w;  w += sizeof(unsigned) * (NB + 1);
    unsigned* cursor    = (unsigned*)w;  w += sizeof(unsigned) * NB;
    float*    pmin      = (float*)w;     w += sizeof(float) * 1024;
    float*    pmax      = (float*)w;     w += sizeof(float) * 1024;
    float*    mm        = (float*)w;     w += sizeof(float) * 4;
    size_t small_needed = (size_t)(w - (char*)d_ws);
    w = (char*)d_ws + ((small_needed + 15) & ~(size_t)15);
    float*    y         = (float*)w;     w += sizeof(float) * (size_t)n;
    size_t full_needed = (size_t)(w - (char*)d_ws);

    const int MMBLOCKS = 1024;
    k_minmax<<<MMBLOCKS, 256, 0, stream>>>(x, n4, pmin, pmax);
    k_setup<<<1, 256, 0, stream>>>(pmin, pmax, MMBLOCKS, params, ranges, score, mm, hist);

    if (ws_size >= full_needed) {
        k_hist<<<256, 256, 0, stream>>>(x, n4, mm, hist);
        k_scan<<<1, 256, 0, stream>>>(hist, bin_start, cursor);
        k_scatter<<<256, 256, 0, stream>>>(x, n4, mm, cursor, y);
        k_binsums<<<NB / 4, 256, 0, stream>>>(y, bin_start, binS1, binS2);
        k_prefix<<<1, 256, 0, stream>>>(binS1, binS2, P1, P2);
        k_score2<<<NCAND, 256, 0, stream>>>(y, bin_start, P1, P2, params, mm, score);
    } else if (ws_size >= small_needed) {
        int nthreads = (n4 + 3) / 4;
        int blocks = (nthreads + 255) / 256;
        k_score_bf<<<blocks, 256, 0, stream>>>(x, n4, params, score);
    }
    k_final<<<1, 64, 0, stream>>>(score, ranges, mm, out, n);
}